// Round 9
// baseline (113.155 us; speedup 1.0000x reference)
//
#include <hip/hip_runtime.h>

#define C 161
#define C3 4173281            // 161^3 cells
#define NVERT_ELEMS 12519843  // C3*3
#define APQ 4121600           // 161*160*160 quads per axis
#define TQ 12364800           // 3*APQ
#define TOTQ_ELEMS 49459200   // 4*TQ
#define NQB 48300             // TQ/256
#define NVBLK 13041           // 161 * 81 (cx × cy-pair), cells along full z

// round f32 to nearest bf16 (RNE), return as f32
__device__ __forceinline__ float bf16r(float f) {
    union { float f; unsigned int u; } v; v.f = f;
    v.u += 0x7FFFu + ((v.u >> 16) & 1u);
    v.u &= 0xFFFF0000u;
    return v.f;
}

// Verts: block = cells (cx, cy0..cy0+1, all z). Stage 6 point-columns of the
// padded grid+deform into LDS with DENSE (4B lane stride) dword copies; pad
// materialized in LDS. Compute entirely from LDS; aligned float4 output.
__global__ __launch_bounds__(256) void verts_kernel(const float* __restrict__ grid,
                                                    const float* __restrict__ deform,
                                                    float* __restrict__ out) {
    __shared__ float sg[6][162];            // padded grid columns   (z 0..161)
    __shared__ float sdef[6][486];          // padded deform columns (z*3+comp)
    __shared__ __align__(16) float sv[966];
    int b = blockIdx.x, t = threadIdx.x;
    int cx = b / 81;
    int cy0 = (b - cx * 81) * 2;
    int NC = (cy0 == 160) ? 161 : 322;      // cells in this block

    // row r: px = cx + (r>=3), py = cy0 + r - 3*(r>=3); valid iff px,py in [1,160]
    // ---- stage grid: 6 x 160 contiguous dwords (lane stride 4B) ----
    for (int p = t; p < 960; p += 256) {
        int r = p / 160;
        int i = p - r * 160;
        int hx = (r >= 3) ? 1 : 0;
        int px = cx + hx;
        int py = cy0 + r - 3 * hx;
        bool valid = ((unsigned)(px - 1) < 160u) & ((unsigned)(py - 1) < 160u);
        int gb = ((px - 1) * 160 + (py - 1)) * 160;
        float v = grid[(valid ? gb : 0) + i];
        sg[r][1 + i] = valid ? v : 1.0f;
    }
    // ---- stage deform: 6 x 480 contiguous dwords (lane stride 4B) ----
    for (int p = t; p < 2880; p += 256) {
        int r = p / 480;
        int j = p - r * 480;
        int hx = (r >= 3) ? 1 : 0;
        int px = cx + hx;
        int py = cy0 + r - 3 * hx;
        bool valid = ((unsigned)(px - 1) < 160u) & ((unsigned)(py - 1) < 160u);
        int db = (((px - 1) * 160 + (py - 1)) * 160) * 3;
        float v = deform[(valid ? db : 0) + j];
        sdef[r][3 + j] = valid ? v : 0.f;
    }
    if (t < 6) {                            // z-pad ends
        sg[t][0] = 1.0f; sg[t][161] = 1.0f;
        sdef[t][0] = 0.f; sdef[t][1] = 0.f; sdef[t][2] = 0.f;
        sdef[t][483] = 0.f; sdef[t][484] = 0.f; sdef[t][485] = 0.f;
    }
    __syncthreads();

    // ---- compute cells from LDS ----
    for (int lc = t; lc < NC; lc += 256) {
        int lr = (lc >= 161) ? 1 : 0;
        int lz = lc - 161 * lr;
        float gv[8], px_[8], py_[8], pz_[8];
#pragma unroll
        for (int c = 0; c < 8; ++c) {
            int bx = (c >> 2) & 1, by = (c >> 1) & 1, dz = c & 1;
            int r = bx * 3 + lr + by;
            int pz = lz + dz;
            gv[c]  = sg[r][pz];
            px_[c] = (float)(cx + bx)       + sdef[r][pz * 3 + 0];
            py_[c] = (float)(cy0 + lr + by) + sdef[r][pz * 3 + 1];
            pz_[c] = (float)pz              + sdef[r][pz * 3 + 2];
        }

        float vs0 = 0.f, vs1 = 0.f, vs2 = 0.f, cnt = 0.f;
#pragma unroll
        for (int a = 0; a < 3; ++a) {
            int step = (a == 0) ? 4 : ((a == 1) ? 2 : 1);
#pragma unroll
            for (int c = 0; c < 8; ++c) {
                if (c & step) continue;
                int c1 = c | step;
                float g0 = gv[c], g1 = gv[c1];
                if ((g0 < 0.f) != (g1 < 0.f)) {
                    float tt = g0 * __builtin_amdgcn_rcpf(g0 - g1);
                    vs0 += px_[c] + tt * (px_[c1] - px_[c]);
                    vs1 += py_[c] + tt * (py_[c1] - py_[c]);
                    vs2 += pz_[c] + tt * (pz_[c1] - pz_[c]);
                    cnt += 1.f;
                }
            }
        }

        float v0, v1, v2;
        if (cnt > 0.f) {
            float inv = __builtin_amdgcn_rcpf(cnt);
            v0 = vs0 * inv; v1 = vs1 * inv; v2 = vs2 * inv;
        } else {
            v0 = v1 = v2 = 0.f;
        }
        const float s = 1.0f / 159.0f;
        sv[lc * 3 + 0] = bf16r((v0 - 1.f) * s);
        sv[lc * 3 + 1] = bf16r((v1 - 1.f) * s);
        sv[lc * 3 + 2] = bf16r((v2 - 1.f) * s);
    }
    __syncthreads();

    // ---- aligned coalesced store of N consecutive floats at out[G..G+N) ----
    int S0 = (cx * 161 + cy0) * 161;
    int N = NC * 3;
    int G = S0 * 3;
    int A = (4 - (G & 3)) & 3;              // scalar head to reach 16B alignment
    if (t < A) out[G + t] = sv[t];
    int main_end = A + ((N - A) & ~3);
    for (int j = A + (t << 2); j < main_end; j += 1024) {
        float4 v;
        v.x = sv[j]; v.y = sv[j + 1]; v.z = sv[j + 2]; v.w = sv[j + 3];
        *(float4*)(out + G + j) = v;
    }
    int k = main_end + t;
    if (k < N) out[G + k] = sv[k];
}

// quad values (elements 0..3, bf16-rounded floats) for quad q; axis-specialized loads
__device__ __forceinline__ float4 quad_vals(const float* __restrict__ grid, int q) {
    int a = q / APQ;
    int rem = q - a * APQ;
    int q0, q1, q2, q3;
    float g0, g1;
    if (a == 0) {
        int i2 = rem % 160; int r = rem / 160; int i1 = r % 160; int i0 = r / 160;
        int ex = i0, ey = i1 + 1, ez = i2 + 1;          // ex in [0,160]
        int pb = i1 * 160 + i2;
        int a0 = max(ex - 1, 0), a1 = min(ex, 159);
        float g0r = grid[a0 * 25600 + pb], g1r = grid[a1 * 25600 + pb];
        g0 = (ex >= 1)   ? g0r : 1.0f;
        g1 = (ex <= 159) ? g1r : 1.0f;
        int b = (ex * C + ey) * C + ez;
        q0 = b - C - 1; q1 = b - 1; q2 = b; q3 = b - C;
    } else if (a == 1) {
        int i2 = rem % 160; int r = rem / 160; int i1 = r % 161; int i0 = r / 161;
        int ex = i0 + 1, ey = i1, ez = i2 + 1;          // ey in [0,160]
        int pb = (ex - 1) * 25600 + i2;
        int a0 = max(ey - 1, 0), a1 = min(ey, 159);
        float g0r = grid[pb + a0 * 160], g1r = grid[pb + a1 * 160];
        g0 = (ey >= 1)   ? g0r : 1.0f;
        g1 = (ey <= 159) ? g1r : 1.0f;
        int b = (ex * C + ey) * C + ez;
        q0 = b - C * C - 1; q1 = b - 1; q2 = b; q3 = b - C * C;
    } else {
        int i2 = rem % 161; int r = rem / 161; int i1 = r % 160; int i0 = r / 160;
        int ex = i0 + 1, ey = i1 + 1, ez = i2;          // ez in [0,160]
        int pb = ((ex - 1) * 160 + i1) * 160;
        int a0 = max(ez - 1, 0), a1 = min(ez, 159);
        float g0r = grid[pb + a0], g1r = grid[pb + a1];
        g0 = (ez >= 1)   ? g0r : 1.0f;
        g1 = (ez <= 159) ? g1r : 1.0f;
        int b = (ex * C + ey) * C + ez;
        q0 = b - C * C - C; q1 = b - C; q2 = b; q3 = b - C * C;
    }
    float4 w;
    bool m = (g0 < 0.f) != (g1 < 0.f);
    if (!m) {
        w.x = w.y = w.z = w.w = -1.0f;
    } else {
        int a0, a1, a2, a3;
        if (g0 < 0.f) { a0 = q0; a1 = q1; a2 = q2; a3 = q3; }
        else          { a0 = q3; a1 = q2; a2 = q1; a3 = q0; }
        w.x = bf16r((float)a0);
        w.y = bf16r((float)a1);
        w.z = bf16r((float)a2);
        w.w = bf16r((float)a3);
    }
    return w;
}

// R5's proven quads: LDS shifted-window for the +1 misalignment, one aligned
// float4 store per thread.
__global__ __launch_bounds__(256) void quads_kernel(const float* __restrict__ grid,
                                                    float* __restrict__ out) {
    __shared__ __align__(16) float sq[1024];
    int b = blockIdx.x, t = threadIdx.x;
    int q = (b << 8) + t;
    float4 w = quad_vals(grid, q);
    // shifted window: sq[i] holds global element NVERT + 1 + 1024*b + i
    sq[(t << 2) + 0] = w.y;
    sq[(t << 2) + 1] = w.z;
    sq[(t << 2) + 2] = w.w;
    if (t > 0) sq[(t << 2) - 1] = w.x;
    if (t == 255) {
        int q2 = q + 1;
        if (q2 < TQ) {
            float4 w2 = quad_vals(grid, q2);
            sq[1023] = w2.x;
        }
    }
    if (b == 0 && t == 0) out[NVERT_ELEMS] = w.x;  // head element

    __syncthreads();
    int avail = TOTQ_ELEMS - 1 - (b << 10);
    if (avail > 1024) avail = 1024;
    int off = t << 2;
    float* gp = out + NVERT_ELEMS + 1 + ((size_t)b << 10);
    if (off + 4 <= avail) {
        float4 v = *(const float4*)&sq[off];
        *(float4*)(gp + off) = v;
    } else if (off < avail) {
        for (int k = off; k < avail; ++k) gp[k] = sq[k];
    }
}

extern "C" void kernel_launch(void* const* d_in, const int* in_sizes, int n_in,
                              void* d_out, int out_size, void* d_ws, size_t ws_size,
                              hipStream_t stream) {
    const float* grid   = (const float*)d_in[0];
    const float* deform = (const float*)d_in[1];
    float* out = (float*)d_out;

    hipLaunchKernelGGL(verts_kernel, dim3(NVBLK), dim3(256), 0, stream, grid, deform, out);
    hipLaunchKernelGGL(quads_kernel, dim3(NQB), dim3(256), 0, stream, grid, out);
}

// Round 10
// 82.389 us; speedup vs baseline: 1.3734x; 1.3734x over previous
//
#include <hip/hip_runtime.h>

#define C 161
#define C3 4173281            // 161^3 cells
#define NVERT_ELEMS 12519843  // C3*3
#define APQ 4121600           // 161*160*160 quads per axis
#define TQ 12364800           // 3*APQ
#define TOTQ_ELEMS 49459200   // 4*TQ
#define NVB 16302             // ceil(C3/256)
#define NQB4 12075            // TQ/1024 (4 quads/thread)

// round f32 to nearest bf16 (RNE), return as f32
__device__ __forceinline__ float bf16r(float f) {
    union { float f; unsigned int u; } v; v.f = f;
    v.u += 0x7FFFu + ((v.u >> 16) & 1u);
    v.u &= 0xFFFF0000u;
    return v.f;
}

// general clamped sample of padded grid (pad 1.0); x,y,z padded coords
__device__ __forceinline__ float sampg(const float* __restrict__ g, int x, int y, int z) {
    int ux = x - 1, uy = y - 1, uz = z - 1;
    bool in = ((unsigned)ux < 160u) && ((unsigned)uy < 160u) && ((unsigned)uz < 160u);
    int cx = min(max(ux, 0), 159);
    int cy = min(max(uy, 0), 159);
    int cz = min(max(uz, 0), 159);
    float v = g[(cx * 160 + cy) * 160 + cz];
    return in ? v : 1.0f;
}

// R5 verts (proven 31 us): one thread per cell, wave-uniform interior fast path.
__global__ __launch_bounds__(256) void verts_kernel(const float* __restrict__ grid,
                                                    const float* __restrict__ deform,
                                                    float* __restrict__ out) {
    __shared__ __align__(16) float sv[768];
    int tid = blockIdx.x * 256 + threadIdx.x;
    int cz = tid % C;
    int t2 = tid / C;
    int cy = t2 % C;
    int cx = t2 / C;

    float gv[8], px[8], py[8], pz[8];
    bool interior = ((unsigned)(cx - 1) < 159u) & ((unsigned)(cy - 1) < 159u) &
                    ((unsigned)(cz - 1) < 159u);
    if (__all(interior)) {
        int base = ((cx - 1) * 160 + (cy - 1)) * 160 + (cz - 1);
#pragma unroll
        for (int c = 0; c < 8; ++c) {
            int bx = (c >> 2) & 1, by = (c >> 1) & 1, bz = c & 1;
            int idx = base + bx * 25600 + by * 160 + bz;
            gv[c] = grid[idx];
            const float* p = deform + (size_t)idx * 3;
            px[c] = (float)(cx + bx) + p[0];
            py[c] = (float)(cy + by) + p[1];
            pz[c] = (float)(cz + bz) + p[2];
        }
    } else {
#pragma unroll
        for (int c = 0; c < 8; ++c) {
            int bx = (c >> 2) & 1, by = (c >> 1) & 1, bz = c & 1;
            int x = cx + bx, y = cy + by, z = cz + bz;
            gv[c] = sampg(grid, x, y, z);
            int ux = x - 1, uy = y - 1, uz = z - 1;
            bool in = ((unsigned)ux < 160u) && ((unsigned)uy < 160u) && ((unsigned)uz < 160u);
            int ix = min(max(ux, 0), 159);
            int iy = min(max(uy, 0), 159);
            int iz = min(max(uz, 0), 159);
            const float* p = deform + ((size_t)((ix * 160 + iy) * 160 + iz)) * 3;
            float a0 = p[0], a1 = p[1], a2 = p[2];
            px[c] = (float)x + (in ? a0 : 0.f);
            py[c] = (float)y + (in ? a1 : 0.f);
            pz[c] = (float)z + (in ? a2 : 0.f);
        }
    }

    float vs0 = 0.f, vs1 = 0.f, vs2 = 0.f, cnt = 0.f;
#pragma unroll
    for (int a = 0; a < 3; ++a) {
        int step = (a == 0) ? 4 : ((a == 1) ? 2 : 1);
#pragma unroll
        for (int c = 0; c < 8; ++c) {
            if (c & step) continue;
            int c1 = c | step;
            float g0 = gv[c], g1 = gv[c1];
            if ((g0 < 0.f) != (g1 < 0.f)) {
                float tt = g0 * __builtin_amdgcn_rcpf(g0 - g1);
                vs0 += px[c] + tt * (px[c1] - px[c]);
                vs1 += py[c] + tt * (py[c1] - py[c]);
                vs2 += pz[c] + tt * (pz[c1] - pz[c]);
                cnt += 1.f;
            }
        }
    }

    float v0, v1, v2;
    if (cnt > 0.f) {
        float inv = __builtin_amdgcn_rcpf(cnt);
        v0 = vs0 * inv; v1 = vs1 * inv; v2 = vs2 * inv;
    } else {
        v0 = v1 = v2 = 0.f;
    }
    const float s = 1.0f / 159.0f;
    int lt = threadIdx.x * 3;
    sv[lt + 0] = bf16r((v0 - 1.f) * s);
    sv[lt + 1] = bf16r((v1 - 1.f) * s);
    sv[lt + 2] = bf16r((v2 - 1.f) * s);

    __syncthreads();
    int base = blockIdx.x * 768;
    int lim = NVERT_ELEMS - base;
    if (lim > 768) lim = 768;
    int off = threadIdx.x << 2;
    if (off + 4 <= lim) {
        float4 v = *(const float4*)&sv[off];
        *(float4*)(out + base + off) = v;
    } else if (off < lim) {
        for (int k = off; k < lim; ++k) out[base + k] = sv[k];
    }
}

// quad values (elements 0..3, bf16-rounded floats) for quad q; axis-specialized loads
__device__ __forceinline__ float4 quad_vals(const float* __restrict__ grid, int q) {
    int a = q / APQ;
    int rem = q - a * APQ;
    int q0, q1, q2, q3;
    float g0, g1;
    if (a == 0) {
        int i2 = rem % 160; int r = rem / 160; int i1 = r % 160; int i0 = r / 160;
        int ex = i0, ey = i1 + 1, ez = i2 + 1;          // ex in [0,160]
        int pb = i1 * 160 + i2;
        int a0 = max(ex - 1, 0), a1 = min(ex, 159);
        float g0r = grid[a0 * 25600 + pb], g1r = grid[a1 * 25600 + pb];
        g0 = (ex >= 1)   ? g0r : 1.0f;
        g1 = (ex <= 159) ? g1r : 1.0f;
        int b = (ex * C + ey) * C + ez;
        q0 = b - C - 1; q1 = b - 1; q2 = b; q3 = b - C;
    } else if (a == 1) {
        int i2 = rem % 160; int r = rem / 160; int i1 = r % 161; int i0 = r / 161;
        int ex = i0 + 1, ey = i1, ez = i2 + 1;          // ey in [0,160]
        int pb = (ex - 1) * 25600 + i2;
        int a0 = max(ey - 1, 0), a1 = min(ey, 159);
        float g0r = grid[pb + a0 * 160], g1r = grid[pb + a1 * 160];
        g0 = (ey >= 1)   ? g0r : 1.0f;
        g1 = (ey <= 159) ? g1r : 1.0f;
        int b = (ex * C + ey) * C + ez;
        q0 = b - C * C - 1; q1 = b - 1; q2 = b; q3 = b - C * C;
    } else {
        int i2 = rem % 161; int r = rem / 161; int i1 = r % 160; int i0 = r / 160;
        int ex = i0 + 1, ey = i1 + 1, ez = i2;          // ez in [0,160]
        int pb = ((ex - 1) * 160 + i1) * 160;
        int a0 = max(ez - 1, 0), a1 = min(ez, 159);
        float g0r = grid[pb + a0], g1r = grid[pb + a1];
        g0 = (ez >= 1)   ? g0r : 1.0f;
        g1 = (ez <= 159) ? g1r : 1.0f;
        int b = (ex * C + ey) * C + ez;
        q0 = b - C * C - C; q1 = b - C; q2 = b; q3 = b - C * C;
    }
    float4 w;
    bool m = (g0 < 0.f) != (g1 < 0.f);
    if (!m) {
        w.x = w.y = w.z = w.w = -1.0f;
    } else {
        int a0, a1, a2, a3;
        if (g0 < 0.f) { a0 = q0; a1 = q1; a2 = q2; a3 = q3; }
        else          { a0 = q3; a1 = q2; a2 = q1; a3 = q0; }
        w.x = bf16r((float)a0);
        w.y = bf16r((float)a1);
        w.z = bf16r((float)a2);
        w.w = bf16r((float)a3);
    }
    return w;
}

// Quads: 4 quads/thread, 1024 quads/block, 16KB LDS shifted window.
// sq[i] holds global element NVERT + 1 + 4096*b + i. Sub-iteration k handles
// quads Q0+256k..Q0+256k+255 (consecutive per wave -> coalescing identical to
// the 1-quad/thread version). Tail element (x of quad Q0+1024) computed ONCE
// per block, at kernel start, so its load latency overlaps all compute.
__global__ __launch_bounds__(256) void quads_kernel(const float* __restrict__ grid,
                                                    float* __restrict__ out) {
    __shared__ __align__(16) float sq[4096];
    int b = blockIdx.x, t = threadIdx.x;
    int Q0 = b << 10;

    if (t == 0 && Q0 + 1024 < TQ)
        sq[4095] = quad_vals(grid, Q0 + 1024).x;   // tail: elem 4096b+4096

#pragma unroll
    for (int k = 0; k < 4; ++k) {
        int j = (k << 8) + t;                       // local quad 0..1023
        float4 w = quad_vals(grid, Q0 + j);
        sq[(j << 2) + 0] = w.y;
        sq[(j << 2) + 1] = w.z;
        sq[(j << 2) + 2] = w.w;
        if (j > 0) sq[(j << 2) - 1] = w.x;
        else if (b == 0) out[NVERT_ELEMS] = w.x;    // global head element
        // (for b>0, elem 4096b is the previous block's tail)
    }
    __syncthreads();

    int avail = TOTQ_ELEMS - 1 - (b << 12);
    if (avail > 4096) avail = 4096;
    float* gp = out + NVERT_ELEMS + 1 + ((size_t)b << 12);
#pragma unroll
    for (int k = 0; k < 4; ++k) {
        int off = (k << 10) + (t << 2);
        if (off + 4 <= avail) {
            float4 v = *(const float4*)&sq[off];
            *(float4*)(gp + off) = v;
        } else if (off < avail) {
            for (int m = off; m < avail; ++m) gp[m] = sq[m];
        }
    }
}

extern "C" void kernel_launch(void* const* d_in, const int* in_sizes, int n_in,
                              void* d_out, int out_size, void* d_ws, size_t ws_size,
                              hipStream_t stream) {
    const float* grid   = (const float*)d_in[0];
    const float* deform = (const float*)d_in[1];
    float* out = (float*)d_out;

    hipLaunchKernelGGL(verts_kernel, dim3(NVB), dim3(256), 0, stream, grid, deform, out);
    hipLaunchKernelGGL(quads_kernel, dim3(NQB4), dim3(256), 0, stream, grid, out);
}

// Round 11
// 82.043 us; speedup vs baseline: 1.3792x; 1.0042x over previous
//
#include <hip/hip_runtime.h>

#define C 161
#define C3 4173281            // 161^3 cells
#define NVERT_ELEMS 12519843  // C3*3
#define APQ 4121600           // 161*160*160 quads per axis
#define TQ 12364800           // 3*APQ
#define NVB 16302             // ceil(C3/256)
#define NQB 48300             // TQ/256

typedef float f32x4 __attribute__((ext_vector_type(4)));

// round f32 to nearest bf16 (RNE), return as f32
__device__ __forceinline__ float bf16r(float f) {
    union { float f; unsigned int u; } v; v.f = f;
    v.u += 0x7FFFu + ((v.u >> 16) & 1u);
    v.u &= 0xFFFF0000u;
    return v.f;
}

// general clamped sample of padded grid (pad 1.0); x,y,z padded coords
__device__ __forceinline__ float sampg(const float* __restrict__ g, int x, int y, int z) {
    int ux = x - 1, uy = y - 1, uz = z - 1;
    bool in = ((unsigned)ux < 160u) && ((unsigned)uy < 160u) && ((unsigned)uz < 160u);
    int cx = min(max(ux, 0), 159);
    int cy = min(max(uy, 0), 159);
    int cz = min(max(uz, 0), 159);
    float v = g[(cx * 160 + cy) * 160 + cz];
    return in ? v : 1.0f;
}

// R5 verts (proven ~31 us): one thread per cell, wave-uniform interior fast path.
__global__ __launch_bounds__(256) void verts_kernel(const float* __restrict__ grid,
                                                    const float* __restrict__ deform,
                                                    float* __restrict__ out) {
    __shared__ __align__(16) float sv[768];
    int tid = blockIdx.x * 256 + threadIdx.x;
    int cz = tid % C;
    int t2 = tid / C;
    int cy = t2 % C;
    int cx = t2 / C;

    float gv[8], px[8], py[8], pz[8];
    bool interior = ((unsigned)(cx - 1) < 159u) & ((unsigned)(cy - 1) < 159u) &
                    ((unsigned)(cz - 1) < 159u);
    if (__all(interior)) {
        int base = ((cx - 1) * 160 + (cy - 1)) * 160 + (cz - 1);
#pragma unroll
        for (int c = 0; c < 8; ++c) {
            int bx = (c >> 2) & 1, by = (c >> 1) & 1, bz = c & 1;
            int idx = base + bx * 25600 + by * 160 + bz;
            gv[c] = grid[idx];
            const float* p = deform + (size_t)idx * 3;
            px[c] = (float)(cx + bx) + p[0];
            py[c] = (float)(cy + by) + p[1];
            pz[c] = (float)(cz + bz) + p[2];
        }
    } else {
#pragma unroll
        for (int c = 0; c < 8; ++c) {
            int bx = (c >> 2) & 1, by = (c >> 1) & 1, bz = c & 1;
            int x = cx + bx, y = cy + by, z = cz + bz;
            gv[c] = sampg(grid, x, y, z);
            int ux = x - 1, uy = y - 1, uz = z - 1;
            bool in = ((unsigned)ux < 160u) && ((unsigned)uy < 160u) && ((unsigned)uz < 160u);
            int ix = min(max(ux, 0), 159);
            int iy = min(max(uy, 0), 159);
            int iz = min(max(uz, 0), 159);
            const float* p = deform + ((size_t)((ix * 160 + iy) * 160 + iz)) * 3;
            float a0 = p[0], a1 = p[1], a2 = p[2];
            px[c] = (float)x + (in ? a0 : 0.f);
            py[c] = (float)y + (in ? a1 : 0.f);
            pz[c] = (float)z + (in ? a2 : 0.f);
        }
    }

    float vs0 = 0.f, vs1 = 0.f, vs2 = 0.f, cnt = 0.f;
#pragma unroll
    for (int a = 0; a < 3; ++a) {
        int step = (a == 0) ? 4 : ((a == 1) ? 2 : 1);
#pragma unroll
        for (int c = 0; c < 8; ++c) {
            if (c & step) continue;
            int c1 = c | step;
            float g0 = gv[c], g1 = gv[c1];
            if ((g0 < 0.f) != (g1 < 0.f)) {
                float tt = g0 * __builtin_amdgcn_rcpf(g0 - g1);
                vs0 += px[c] + tt * (px[c1] - px[c]);
                vs1 += py[c] + tt * (py[c1] - py[c]);
                vs2 += pz[c] + tt * (pz[c1] - pz[c]);
                cnt += 1.f;
            }
        }
    }

    float v0, v1, v2;
    if (cnt > 0.f) {
        float inv = __builtin_amdgcn_rcpf(cnt);
        v0 = vs0 * inv; v1 = vs1 * inv; v2 = vs2 * inv;
    } else {
        v0 = v1 = v2 = 0.f;
    }
    const float s = 1.0f / 159.0f;
    int lt = threadIdx.x * 3;
    sv[lt + 0] = bf16r((v0 - 1.f) * s);
    sv[lt + 1] = bf16r((v1 - 1.f) * s);
    sv[lt + 2] = bf16r((v2 - 1.f) * s);

    __syncthreads();
    int base = blockIdx.x * 768;
    int lim = NVERT_ELEMS - base;
    if (lim > 768) lim = 768;
    int off = threadIdx.x << 2;
    if (off + 4 <= lim) {
        float4 v = *(const float4*)&sv[off];
        *(float4*)(out + base + off) = v;
    } else if (off < lim) {
        for (int k = off; k < lim; ++k) out[base + k] = sv[k];
    }
}

// quad values (elements 0..3, bf16-rounded floats) for quad q; axis-specialized loads
__device__ __forceinline__ f32x4 quad_vals(const float* __restrict__ grid, int q) {
    int a = q / APQ;
    int rem = q - a * APQ;
    int q0, q1, q2, q3;
    float g0, g1;
    if (a == 0) {
        int i2 = rem % 160; int r = rem / 160; int i1 = r % 160; int i0 = r / 160;
        int ex = i0, ey = i1 + 1, ez = i2 + 1;          // ex in [0,160]
        int pb = i1 * 160 + i2;
        int a0 = max(ex - 1, 0), a1 = min(ex, 159);
        float g0r = grid[a0 * 25600 + pb], g1r = grid[a1 * 25600 + pb];
        g0 = (ex >= 1)   ? g0r : 1.0f;
        g1 = (ex <= 159) ? g1r : 1.0f;
        int b = (ex * C + ey) * C + ez;
        q0 = b - C - 1; q1 = b - 1; q2 = b; q3 = b - C;
    } else if (a == 1) {
        int i2 = rem % 160; int r = rem / 160; int i1 = r % 161; int i0 = r / 161;
        int ex = i0 + 1, ey = i1, ez = i2 + 1;          // ey in [0,160]
        int pb = (ex - 1) * 25600 + i2;
        int a0 = max(ey - 1, 0), a1 = min(ey, 159);
        float g0r = grid[pb + a0 * 160], g1r = grid[pb + a1 * 160];
        g0 = (ey >= 1)   ? g0r : 1.0f;
        g1 = (ey <= 159) ? g1r : 1.0f;
        int b = (ex * C + ey) * C + ez;
        q0 = b - C * C - 1; q1 = b - 1; q2 = b; q3 = b - C * C;
    } else {
        int i2 = rem % 161; int r = rem / 161; int i1 = r % 160; int i0 = r / 160;
        int ex = i0 + 1, ey = i1 + 1, ez = i2;          // ez in [0,160]
        int pb = ((ex - 1) * 160 + i1) * 160;
        int a0 = max(ez - 1, 0), a1 = min(ez, 159);
        float g0r = grid[pb + a0], g1r = grid[pb + a1];
        g0 = (ez >= 1)   ? g0r : 1.0f;
        g1 = (ez <= 159) ? g1r : 1.0f;
        int b = (ex * C + ey) * C + ez;
        q0 = b - C * C - C; q1 = b - C; q2 = b; q3 = b - C * C;
    }
    f32x4 w;
    bool m = (g0 < 0.f) != (g1 < 0.f);
    if (!m) {
        w.x = w.y = w.z = w.w = -1.0f;
    } else {
        int a0, a1, a2, a3;
        if (g0 < 0.f) { a0 = q0; a1 = q1; a2 = q2; a3 = q3; }
        else          { a0 = q3; a1 = q2; a2 = q1; a3 = q0; }
        w.x = bf16r((float)a0);
        w.y = bf16r((float)a1);
        w.z = bf16r((float)a2);
        w.w = bf16r((float)a3);
    }
    return w;
}

// Direct quads: thread q computes quad q and stores its 4 elements at
// out + NVERT + 4q (4B-aligned; gfx9 global_store_dwordx4 only needs dword
// alignment). Lane stride 16B -> contiguous 1KB span per wave-instruction.
// No LDS, no barrier, no head/tail cases. Inline asm guarantees a single
// dwordx4 (C++ float4 would promise align-16 / risk a 4-way dword split).
__global__ __launch_bounds__(256) void quads_kernel(const float* __restrict__ grid,
                                                    float* __restrict__ out) {
    int q = blockIdx.x * 256 + threadIdx.x;   // TQ = NQB*256 exactly
    f32x4 w = quad_vals(grid, q);
    float* gp = out + NVERT_ELEMS + ((size_t)q << 2);
    asm volatile("global_store_dwordx4 %0, %1, off"
                 :: "v"(gp), "v"(w) : "memory");
}

extern "C" void kernel_launch(void* const* d_in, const int* in_sizes, int n_in,
                              void* d_out, int out_size, void* d_ws, size_t ws_size,
                              hipStream_t stream) {
    const float* grid   = (const float*)d_in[0];
    const float* deform = (const float*)d_in[1];
    float* out = (float*)d_out;

    hipLaunchKernelGGL(verts_kernel, dim3(NVB), dim3(256), 0, stream, grid, deform, out);
    hipLaunchKernelGGL(quads_kernel, dim3(NQB), dim3(256), 0, stream, grid, out);
}

// Round 12
// 78.825 us; speedup vs baseline: 1.4355x; 1.0408x over previous
//
#include <hip/hip_runtime.h>

#define C 161
#define C3 4173281            // 161^3 cells
#define NVERT_ELEMS 12519843  // C3*3
#define APQ 4121600           // 161*160*160 quads per axis
#define TQ 12364800           // 3*APQ
#define NVB 16302             // ceil(C3/256)
#define NQB 48300             // TQ/256
#define NTOT 64602            // NVB + NQB

typedef float f32x4 __attribute__((ext_vector_type(4)));

// round f32 to nearest bf16 (RNE), return as f32
__device__ __forceinline__ float bf16r(float f) {
    union { float f; unsigned int u; } v; v.f = f;
    v.u += 0x7FFFu + ((v.u >> 16) & 1u);
    v.u &= 0xFFFF0000u;
    return v.f;
}

// general clamped sample of padded grid (pad 1.0); x,y,z padded coords
__device__ __forceinline__ float sampg(const float* __restrict__ g, int x, int y, int z) {
    int ux = x - 1, uy = y - 1, uz = z - 1;
    bool in = ((unsigned)ux < 160u) && ((unsigned)uy < 160u) && ((unsigned)uz < 160u);
    int cx = min(max(ux, 0), 159);
    int cy = min(max(uy, 0), 159);
    int cz = min(max(uz, 0), 159);
    float v = g[(cx * 160 + cy) * 160 + cz];
    return in ? v : 1.0f;
}

// R5 verts body (proven ~31 us): one thread per cell, wave-uniform interior
// fast path, LDS-staged aligned float4 output.
__device__ __forceinline__ void verts_body(int vb, int t,
                                           const float* __restrict__ grid,
                                           const float* __restrict__ deform,
                                           float* __restrict__ out,
                                           float* sv) {
    int tid = vb * 256 + t;
    int cz = tid % C;
    int t2 = tid / C;
    int cy = t2 % C;
    int cx = t2 / C;

    float gv[8], px[8], py[8], pz[8];
    bool interior = ((unsigned)(cx - 1) < 159u) & ((unsigned)(cy - 1) < 159u) &
                    ((unsigned)(cz - 1) < 159u);
    if (__all(interior)) {
        int base = ((cx - 1) * 160 + (cy - 1)) * 160 + (cz - 1);
#pragma unroll
        for (int c = 0; c < 8; ++c) {
            int bx = (c >> 2) & 1, by = (c >> 1) & 1, bz = c & 1;
            int idx = base + bx * 25600 + by * 160 + bz;
            gv[c] = grid[idx];
            const float* p = deform + (size_t)idx * 3;
            px[c] = (float)(cx + bx) + p[0];
            py[c] = (float)(cy + by) + p[1];
            pz[c] = (float)(cz + bz) + p[2];
        }
    } else {
#pragma unroll
        for (int c = 0; c < 8; ++c) {
            int bx = (c >> 2) & 1, by = (c >> 1) & 1, bz = c & 1;
            int x = cx + bx, y = cy + by, z = cz + bz;
            gv[c] = sampg(grid, x, y, z);
            int ux = x - 1, uy = y - 1, uz = z - 1;
            bool in = ((unsigned)ux < 160u) && ((unsigned)uy < 160u) && ((unsigned)uz < 160u);
            int ix = min(max(ux, 0), 159);
            int iy = min(max(uy, 0), 159);
            int iz = min(max(uz, 0), 159);
            const float* p = deform + ((size_t)((ix * 160 + iy) * 160 + iz)) * 3;
            float a0 = p[0], a1 = p[1], a2 = p[2];
            px[c] = (float)x + (in ? a0 : 0.f);
            py[c] = (float)y + (in ? a1 : 0.f);
            pz[c] = (float)z + (in ? a2 : 0.f);
        }
    }

    float vs0 = 0.f, vs1 = 0.f, vs2 = 0.f, cnt = 0.f;
#pragma unroll
    for (int a = 0; a < 3; ++a) {
        int step = (a == 0) ? 4 : ((a == 1) ? 2 : 1);
#pragma unroll
        for (int c = 0; c < 8; ++c) {
            if (c & step) continue;
            int c1 = c | step;
            float g0 = gv[c], g1 = gv[c1];
            if ((g0 < 0.f) != (g1 < 0.f)) {
                float tt = g0 * __builtin_amdgcn_rcpf(g0 - g1);
                vs0 += px[c] + tt * (px[c1] - px[c]);
                vs1 += py[c] + tt * (py[c1] - py[c]);
                vs2 += pz[c] + tt * (pz[c1] - pz[c]);
                cnt += 1.f;
            }
        }
    }

    float v0, v1, v2;
    if (cnt > 0.f) {
        float inv = __builtin_amdgcn_rcpf(cnt);
        v0 = vs0 * inv; v1 = vs1 * inv; v2 = vs2 * inv;
    } else {
        v0 = v1 = v2 = 0.f;
    }
    const float s = 1.0f / 159.0f;
    int lt = t * 3;
    sv[lt + 0] = bf16r((v0 - 1.f) * s);
    sv[lt + 1] = bf16r((v1 - 1.f) * s);
    sv[lt + 2] = bf16r((v2 - 1.f) * s);

    __syncthreads();
    int base = vb * 768;
    int lim = NVERT_ELEMS - base;
    if (lim > 768) lim = 768;
    int off = t << 2;
    if (off + 4 <= lim) {
        float4 v = *(const float4*)&sv[off];
        *(float4*)(out + base + off) = v;
    } else if (off < lim) {
        for (int k = off; k < lim; ++k) out[base + k] = sv[k];
    }
}

// quad values (elements 0..3, bf16-rounded floats) for quad q; axis-specialized loads
__device__ __forceinline__ f32x4 quad_vals(const float* __restrict__ grid, int q) {
    int a = q / APQ;
    int rem = q - a * APQ;
    int q0, q1, q2, q3;
    float g0, g1;
    if (a == 0) {
        int i2 = rem % 160; int r = rem / 160; int i1 = r % 160; int i0 = r / 160;
        int ex = i0, ey = i1 + 1, ez = i2 + 1;          // ex in [0,160]
        int pb = i1 * 160 + i2;
        int a0 = max(ex - 1, 0), a1 = min(ex, 159);
        float g0r = grid[a0 * 25600 + pb], g1r = grid[a1 * 25600 + pb];
        g0 = (ex >= 1)   ? g0r : 1.0f;
        g1 = (ex <= 159) ? g1r : 1.0f;
        int b = (ex * C + ey) * C + ez;
        q0 = b - C - 1; q1 = b - 1; q2 = b; q3 = b - C;
    } else if (a == 1) {
        int i2 = rem % 160; int r = rem / 160; int i1 = r % 161; int i0 = r / 161;
        int ex = i0 + 1, ey = i1, ez = i2 + 1;          // ey in [0,160]
        int pb = (ex - 1) * 25600 + i2;
        int a0 = max(ey - 1, 0), a1 = min(ey, 159);
        float g0r = grid[pb + a0 * 160], g1r = grid[pb + a1 * 160];
        g0 = (ey >= 1)   ? g0r : 1.0f;
        g1 = (ey <= 159) ? g1r : 1.0f;
        int b = (ex * C + ey) * C + ez;
        q0 = b - C * C - 1; q1 = b - 1; q2 = b; q3 = b - C * C;
    } else {
        int i2 = rem % 161; int r = rem / 161; int i1 = r % 160; int i0 = r / 160;
        int ex = i0 + 1, ey = i1 + 1, ez = i2;          // ez in [0,160]
        int pb = ((ex - 1) * 160 + i1) * 160;
        int a0 = max(ez - 1, 0), a1 = min(ez, 159);
        float g0r = grid[pb + a0], g1r = grid[pb + a1];
        g0 = (ez >= 1)   ? g0r : 1.0f;
        g1 = (ez <= 159) ? g1r : 1.0f;
        int b = (ex * C + ey) * C + ez;
        q0 = b - C * C - C; q1 = b - C; q2 = b; q3 = b - C * C;
    }
    f32x4 w;
    bool m = (g0 < 0.f) != (g1 < 0.f);
    if (!m) {
        w.x = w.y = w.z = w.w = -1.0f;
    } else {
        int a0, a1, a2, a3;
        if (g0 < 0.f) { a0 = q0; a1 = q1; a2 = q2; a3 = q3; }
        else          { a0 = q3; a1 = q2; a2 = q1; a3 = q0; }
        w.x = bf16r((float)a0);
        w.y = bf16r((float)a1);
        w.z = bf16r((float)a2);
        w.w = bf16r((float)a3);
    }
    return w;
}

// R11 quads body: direct misaligned dwordx4 store (4B-aligned is legal),
// lane stride 16B -> contiguous 1KB span per wave-instruction.
__device__ __forceinline__ void quads_body(int qb, int t,
                                           const float* __restrict__ grid,
                                           float* __restrict__ out) {
    int q = qb * 256 + t;                 // TQ = NQB*256 exactly
    f32x4 w = quad_vals(grid, q);
    float* gp = out + NVERT_ELEMS + ((size_t)q << 2);
    asm volatile("global_store_dwordx4 %0, %1, off"
                 :: "v"(gp), "v"(w) : "memory");
}

// Concatenated fusion: blocks [0,NVB) run verts, [NVB,NTOT) run quads.
// Phase purity preserved (unlike R4's interleave); removes the inter-kernel
// drain bubble and overlaps verts' tail with quads' ramp.
__global__ __launch_bounds__(256) void dmc_fused(const float* __restrict__ grid,
                                                 const float* __restrict__ deform,
                                                 float* __restrict__ out) {
    __shared__ __align__(16) float sv[768];
    int b = blockIdx.x, t = threadIdx.x;
    if (b < NVB) {
        verts_body(b, t, grid, deform, out, sv);
    } else {
        quads_body(b - NVB, t, grid, out);
    }
}

extern "C" void kernel_launch(void* const* d_in, const int* in_sizes, int n_in,
                              void* d_out, int out_size, void* d_ws, size_t ws_size,
                              hipStream_t stream) {
    const float* grid   = (const float*)d_in[0];
    const float* deform = (const float*)d_in[1];
    float* out = (float*)d_out;

    hipLaunchKernelGGL(dmc_fused, dim3(NTOT), dim3(256), 0, stream, grid, deform, out);
}

// Round 14
// 78.727 us; speedup vs baseline: 1.4373x; 1.0013x over previous
//
#include <hip/hip_runtime.h>

#define C 161
#define C3 4173281            // 161^3 cells
#define NVERT_ELEMS 12519843  // C3*3
#define APQ 4121600           // 161*160*160 quads per axis
#define TQ 12364800           // 3*APQ
#define NVB 16302             // ceil(C3/256)
#define NQB 48300             // TQ/256 = 3*16100
#define QBPA 16100            // quad blocks per axis (APQ/256)
#define NTOT 64602            // NVB + NQB
#define LAST_INTERIOR_TID 4147197  // cell (159,159,159): corner reads last deform elem

typedef float f32x4 __attribute__((ext_vector_type(4)));

// round f32 to nearest bf16 (RNE), return as f32
__device__ __forceinline__ float bf16r(float f) {
    union { float f; unsigned int u; } v; v.f = f;
    v.u += 0x7FFFu + ((v.u >> 16) & 1u);
    v.u &= 0xFFFF0000u;
    return v.f;
}

// general clamped sample of padded grid (pad 1.0); x,y,z padded coords
__device__ __forceinline__ float sampg(const float* __restrict__ g, int x, int y, int z) {
    int ux = x - 1, uy = y - 1, uz = z - 1;
    bool in = ((unsigned)ux < 160u) && ((unsigned)uy < 160u) && ((unsigned)uz < 160u);
    int cx = min(max(ux, 0), 159);
    int cy = min(max(uy, 0), 159);
    int cz = min(max(uz, 0), 159);
    float v = g[(cx * 160 + cy) * 160 + cz];
    return in ? v : 1.0f;
}

// Verts body: one thread per cell. Fast path: 8 compiler grid loads + 8 asm
// deform dwordx4 loads (dword-aligned x4 legal, cf. R11 store). The waitcnt
// asm takes dr[*] as "+v" TIED operands: consumers data-depend on the
// post-drain values, so the scheduler cannot hoist them above the wait
// (a bare "memory"-clobber waitcnt does NOT order register-only consumers).
__device__ __forceinline__ void verts_body(int vb, int t,
                                           const float* __restrict__ grid,
                                           const float* __restrict__ deform,
                                           float* __restrict__ out,
                                           float* sv) {
    int tid = vb * 256 + t;
    int cz = tid % C;
    int t2 = tid / C;
    int cy = t2 % C;
    int cx = t2 / C;

    float gv[8], px[8], py[8], pz[8];
    bool interior = ((unsigned)(cx - 1) < 159u) & ((unsigned)(cy - 1) < 159u) &
                    ((unsigned)(cz - 1) < 159u) & (tid != LAST_INTERIOR_TID);
    if (__all(interior)) {
        int base = ((cx - 1) * 160 + (cy - 1)) * 160 + (cz - 1);
        f32x4 dr[8];
#pragma unroll
        for (int c = 0; c < 8; ++c) {
            int bx = (c >> 2) & 1, by = (c >> 1) & 1, bz = c & 1;
            int idx = base + bx * 25600 + by * 160 + bz;
            asm volatile("global_load_dwordx4 %0, %1, off"
                         : "=v"(dr[c]) : "v"(deform + (size_t)idx * 3));
            gv[c] = grid[idx];          // compiler-managed load + its own waitcnt
        }
        asm volatile("s_waitcnt vmcnt(0)"
                     : "+v"(dr[0]), "+v"(dr[1]), "+v"(dr[2]), "+v"(dr[3]),
                       "+v"(dr[4]), "+v"(dr[5]), "+v"(dr[6]), "+v"(dr[7])
                     :: "memory");
        __builtin_amdgcn_sched_barrier(0);
#pragma unroll
        for (int c = 0; c < 8; ++c) {
            int bx = (c >> 2) & 1, by = (c >> 1) & 1, bz = c & 1;
            px[c] = (float)(cx + bx) + dr[c].x;
            py[c] = (float)(cy + by) + dr[c].y;
            pz[c] = (float)(cz + bz) + dr[c].z;
        }
    } else {
#pragma unroll
        for (int c = 0; c < 8; ++c) {
            int bx = (c >> 2) & 1, by = (c >> 1) & 1, bz = c & 1;
            int x = cx + bx, y = cy + by, z = cz + bz;
            gv[c] = sampg(grid, x, y, z);
            int ux = x - 1, uy = y - 1, uz = z - 1;
            bool in = ((unsigned)ux < 160u) && ((unsigned)uy < 160u) && ((unsigned)uz < 160u);
            int ix = min(max(ux, 0), 159);
            int iy = min(max(uy, 0), 159);
            int iz = min(max(uz, 0), 159);
            const float* p = deform + ((size_t)((ix * 160 + iy) * 160 + iz)) * 3;
            float a0 = p[0], a1 = p[1], a2 = p[2];
            px[c] = (float)x + (in ? a0 : 0.f);
            py[c] = (float)y + (in ? a1 : 0.f);
            pz[c] = (float)z + (in ? a2 : 0.f);
        }
    }

    float vs0 = 0.f, vs1 = 0.f, vs2 = 0.f, cnt = 0.f;
#pragma unroll
    for (int a = 0; a < 3; ++a) {
        int step = (a == 0) ? 4 : ((a == 1) ? 2 : 1);
#pragma unroll
        for (int c = 0; c < 8; ++c) {
            if (c & step) continue;
            int c1 = c | step;
            float g0 = gv[c], g1 = gv[c1];
            if ((g0 < 0.f) != (g1 < 0.f)) {
                float tt = g0 * __builtin_amdgcn_rcpf(g0 - g1);
                vs0 += px[c] + tt * (px[c1] - px[c]);
                vs1 += py[c] + tt * (py[c1] - py[c]);
                vs2 += pz[c] + tt * (pz[c1] - pz[c]);
                cnt += 1.f;
            }
        }
    }

    float v0, v1, v2;
    if (cnt > 0.f) {
        float inv = __builtin_amdgcn_rcpf(cnt);
        v0 = vs0 * inv; v1 = vs1 * inv; v2 = vs2 * inv;
    } else {
        v0 = v1 = v2 = 0.f;
    }
    const float s = 1.0f / 159.0f;
    int lt = t * 3;
    sv[lt + 0] = bf16r((v0 - 1.f) * s);
    sv[lt + 1] = bf16r((v1 - 1.f) * s);
    sv[lt + 2] = bf16r((v2 - 1.f) * s);

    __syncthreads();
    int base = vb * 768;
    int lim = NVERT_ELEMS - base;
    if (lim > 768) lim = 768;
    int off = t << 2;
    if (off + 4 <= lim) {
        float4 v = *(const float4*)&sv[off];
        *(float4*)(out + base + off) = v;
    } else if (off < lim) {
        for (int k = off; k < lim; ++k) out[base + k] = sv[k];
    }
}

// quad values for quad (axis a, index rem); axis-specialized loads
__device__ __forceinline__ f32x4 quad_vals(const float* __restrict__ grid,
                                           int a, int rem) {
    int q0, q1, q2, q3;
    float g0, g1;
    if (a == 0) {
        int i2 = rem % 160; int r = rem / 160; int i1 = r % 160; int i0 = r / 160;
        int ex = i0, ey = i1 + 1, ez = i2 + 1;          // ex in [0,160]
        int pb = i1 * 160 + i2;
        int a0 = max(ex - 1, 0), a1 = min(ex, 159);
        float g0r = grid[a0 * 25600 + pb], g1r = grid[a1 * 25600 + pb];
        g0 = (ex >= 1)   ? g0r : 1.0f;
        g1 = (ex <= 159) ? g1r : 1.0f;
        int b = (ex * C + ey) * C + ez;
        q0 = b - C - 1; q1 = b - 1; q2 = b; q3 = b - C;
    } else if (a == 1) {
        int i2 = rem % 160; int r = rem / 160; int i1 = r % 161; int i0 = r / 161;
        int ex = i0 + 1, ey = i1, ez = i2 + 1;          // ey in [0,160]
        int pb = (ex - 1) * 25600 + i2;
        int a0 = max(ey - 1, 0), a1 = min(ey, 159);
        float g0r = grid[pb + a0 * 160], g1r = grid[pb + a1 * 160];
        g0 = (ey >= 1)   ? g0r : 1.0f;
        g1 = (ey <= 159) ? g1r : 1.0f;
        int b = (ex * C + ey) * C + ez;
        q0 = b - C * C - 1; q1 = b - 1; q2 = b; q3 = b - C * C;
    } else {
        int i2 = rem % 161; int r = rem / 161; int i1 = r % 160; int i0 = r / 160;
        int ex = i0 + 1, ey = i1 + 1, ez = i2;          // ez in [0,160]
        int pb = ((ex - 1) * 160 + i1) * 160;
        int a0 = max(ez - 1, 0), a1 = min(ez, 159);
        float g0r = grid[pb + a0], g1r = grid[pb + a1];
        g0 = (ez >= 1)   ? g0r : 1.0f;
        g1 = (ez <= 159) ? g1r : 1.0f;
        int b = (ex * C + ey) * C + ez;
        q0 = b - C * C - C; q1 = b - C; q2 = b; q3 = b - C * C;
    }
    f32x4 w;
    bool m = (g0 < 0.f) != (g1 < 0.f);
    if (!m) {
        w.x = w.y = w.z = w.w = -1.0f;
    } else {
        int a0, a1, a2, a3;
        if (g0 < 0.f) { a0 = q0; a1 = q1; a2 = q2; a3 = q3; }
        else          { a0 = q3; a1 = q2; a2 = q1; a3 = q0; }
        w.x = bf16r((float)a0);
        w.y = bf16r((float)a1);
        w.z = bf16r((float)a2);
        w.w = bf16r((float)a3);
    }
    return w;
}

// Quads body: direct misaligned dwordx4 store; wave-uniform axis decode
// (qb/16100 is per-block scalar; q = a*APQ + lb*256 + t, identical mapping).
__device__ __forceinline__ void quads_body(int qb, int t,
                                           const float* __restrict__ grid,
                                           float* __restrict__ out) {
    int a = qb / QBPA;
    int lb = qb - a * QBPA;
    int rem = lb * 256 + t;
    f32x4 w = quad_vals(grid, a, rem);
    int q = a * APQ + rem;
    float* gp = out + NVERT_ELEMS + ((size_t)q << 2);
    asm volatile("global_store_dwordx4 %0, %1, off"
                 :: "v"(gp), "v"(w) : "memory");
}

// Concatenated fusion: blocks [0,NVB) run verts, [NVB,NTOT) run quads.
__global__ __launch_bounds__(256) void dmc_fused(const float* __restrict__ grid,
                                                 const float* __restrict__ deform,
                                                 float* __restrict__ out) {
    __shared__ __align__(16) float sv[768];
    int b = blockIdx.x, t = threadIdx.x;
    if (b < NVB) {
        verts_body(b, t, grid, deform, out, sv);
    } else {
        quads_body(b - NVB, t, grid, out);
    }
}

extern "C" void kernel_launch(void* const* d_in, const int* in_sizes, int n_in,
                              void* d_out, int out_size, void* d_ws, size_t ws_size,
                              hipStream_t stream) {
    const float* grid   = (const float*)d_in[0];
    const float* deform = (const float*)d_in[1];
    float* out = (float*)d_out;

    hipLaunchKernelGGL(dmc_fused, dim3(NTOT), dim3(256), 0, stream, grid, deform, out);
}

// Round 16
// 78.443 us; speedup vs baseline: 1.4425x; 1.0036x over previous
//
#include <hip/hip_runtime.h>

#define C 161
#define C3 4173281            // 161^3 cells
#define NVERT_ELEMS 12519843  // C3*3
#define APQ 4121600           // 161*160*160 quads per axis
#define TQ 12364800           // 3*APQ
#define NVB 16302             // ceil(C3/256)
#define NQB 48300             // TQ/256 = 3*16100
#define QBPA 16100            // quad blocks per axis (APQ/256)
#define NTOT 64602            // NVB + NQB
#define LAST_INTERIOR_TID 4147197  // cell (159,159,159): corner reads last deform elem

typedef float f32x4 __attribute__((ext_vector_type(4)));

// round f32 to nearest bf16 (RNE), return as f32
__device__ __forceinline__ float bf16r(float f) {
    union { float f; unsigned int u; } v; v.f = f;
    v.u += 0x7FFFu + ((v.u >> 16) & 1u);
    v.u &= 0xFFFF0000u;
    return v.f;
}

// general clamped sample of padded grid (pad 1.0); x,y,z padded coords
__device__ __forceinline__ float sampg(const float* __restrict__ g, int x, int y, int z) {
    int ux = x - 1, uy = y - 1, uz = z - 1;
    bool in = ((unsigned)ux < 160u) && ((unsigned)uy < 160u) && ((unsigned)uz < 160u);
    int cx = min(max(ux, 0), 159);
    int cy = min(max(uy, 0), 159);
    int cz = min(max(uz, 0), 159);
    float v = g[(cx * 160 + cy) * 160 + cz];
    return in ? v : 1.0f;
}

// Verts body (R14, proven): fast path = 8 compiler grid loads + 8 asm deform
// dwordx4 loads; waitcnt with "+v" tied operands so consumers can't hoist.
// Output store is NON-TEMPORAL: output is write-once, never read -- keep it
// out of L2 so grid/deform stay resident.
__device__ __forceinline__ void verts_body(int vb, int t,
                                           const float* __restrict__ grid,
                                           const float* __restrict__ deform,
                                           float* __restrict__ out,
                                           float* sv) {
    int tid = vb * 256 + t;
    int cz = tid % C;
    int t2 = tid / C;
    int cy = t2 % C;
    int cx = t2 / C;

    float gv[8], px[8], py[8], pz[8];
    bool interior = ((unsigned)(cx - 1) < 159u) & ((unsigned)(cy - 1) < 159u) &
                    ((unsigned)(cz - 1) < 159u) & (tid != LAST_INTERIOR_TID);
    if (__all(interior)) {
        int base = ((cx - 1) * 160 + (cy - 1)) * 160 + (cz - 1);
        f32x4 dr[8];
#pragma unroll
        for (int c = 0; c < 8; ++c) {
            int bx = (c >> 2) & 1, by = (c >> 1) & 1, bz = c & 1;
            int idx = base + bx * 25600 + by * 160 + bz;
            asm volatile("global_load_dwordx4 %0, %1, off"
                         : "=v"(dr[c]) : "v"(deform + (size_t)idx * 3));
            gv[c] = grid[idx];          // compiler-managed load + its own waitcnt
        }
        asm volatile("s_waitcnt vmcnt(0)"
                     : "+v"(dr[0]), "+v"(dr[1]), "+v"(dr[2]), "+v"(dr[3]),
                       "+v"(dr[4]), "+v"(dr[5]), "+v"(dr[6]), "+v"(dr[7])
                     :: "memory");
        __builtin_amdgcn_sched_barrier(0);
#pragma unroll
        for (int c = 0; c < 8; ++c) {
            int bx = (c >> 2) & 1, by = (c >> 1) & 1, bz = c & 1;
            px[c] = (float)(cx + bx) + dr[c].x;
            py[c] = (float)(cy + by) + dr[c].y;
            pz[c] = (float)(cz + bz) + dr[c].z;
        }
    } else {
#pragma unroll
        for (int c = 0; c < 8; ++c) {
            int bx = (c >> 2) & 1, by = (c >> 1) & 1, bz = c & 1;
            int x = cx + bx, y = cy + by, z = cz + bz;
            gv[c] = sampg(grid, x, y, z);
            int ux = x - 1, uy = y - 1, uz = z - 1;
            bool in = ((unsigned)ux < 160u) && ((unsigned)uy < 160u) && ((unsigned)uz < 160u);
            int ix = min(max(ux, 0), 159);
            int iy = min(max(uy, 0), 159);
            int iz = min(max(uz, 0), 159);
            const float* p = deform + ((size_t)((ix * 160 + iy) * 160 + iz)) * 3;
            float a0 = p[0], a1 = p[1], a2 = p[2];
            px[c] = (float)x + (in ? a0 : 0.f);
            py[c] = (float)y + (in ? a1 : 0.f);
            pz[c] = (float)z + (in ? a2 : 0.f);
        }
    }

    float vs0 = 0.f, vs1 = 0.f, vs2 = 0.f, cnt = 0.f;
#pragma unroll
    for (int a = 0; a < 3; ++a) {
        int step = (a == 0) ? 4 : ((a == 1) ? 2 : 1);
#pragma unroll
        for (int c = 0; c < 8; ++c) {
            if (c & step) continue;
            int c1 = c | step;
            float g0 = gv[c], g1 = gv[c1];
            if ((g0 < 0.f) != (g1 < 0.f)) {
                float tt = g0 * __builtin_amdgcn_rcpf(g0 - g1);
                vs0 += px[c] + tt * (px[c1] - px[c]);
                vs1 += py[c] + tt * (py[c1] - py[c]);
                vs2 += pz[c] + tt * (pz[c1] - pz[c]);
                cnt += 1.f;
            }
        }
    }

    float v0, v1, v2;
    if (cnt > 0.f) {
        float inv = __builtin_amdgcn_rcpf(cnt);
        v0 = vs0 * inv; v1 = vs1 * inv; v2 = vs2 * inv;
    } else {
        v0 = v1 = v2 = 0.f;
    }
    const float s = 1.0f / 159.0f;
    int lt = t * 3;
    sv[lt + 0] = bf16r((v0 - 1.f) * s);
    sv[lt + 1] = bf16r((v1 - 1.f) * s);
    sv[lt + 2] = bf16r((v2 - 1.f) * s);

    __syncthreads();
    int base = vb * 768;
    int lim = NVERT_ELEMS - base;
    if (lim > 768) lim = 768;
    int off = t << 2;
    if (off + 4 <= lim) {
        f32x4 v = *(const f32x4*)&sv[off];
        __builtin_nontemporal_store(v, (f32x4*)(out + base + off));
    } else if (off < lim) {
        for (int k = off; k < lim; ++k) out[base + k] = sv[k];
    }
}

// quad values for quad (axis a, index rem); axis-specialized loads
__device__ __forceinline__ f32x4 quad_vals(const float* __restrict__ grid,
                                           int a, int rem) {
    int q0, q1, q2, q3;
    float g0, g1;
    if (a == 0) {
        int i2 = rem % 160; int r = rem / 160; int i1 = r % 160; int i0 = r / 160;
        int ex = i0, ey = i1 + 1, ez = i2 + 1;          // ex in [0,160]
        int pb = i1 * 160 + i2;
        int a0 = max(ex - 1, 0), a1 = min(ex, 159);
        float g0r = grid[a0 * 25600 + pb], g1r = grid[a1 * 25600 + pb];
        g0 = (ex >= 1)   ? g0r : 1.0f;
        g1 = (ex <= 159) ? g1r : 1.0f;
        int b = (ex * C + ey) * C + ez;
        q0 = b - C - 1; q1 = b - 1; q2 = b; q3 = b - C;
    } else if (a == 1) {
        int i2 = rem % 160; int r = rem / 160; int i1 = r % 161; int i0 = r / 161;
        int ex = i0 + 1, ey = i1, ez = i2 + 1;          // ey in [0,160]
        int pb = (ex - 1) * 25600 + i2;
        int a0 = max(ey - 1, 0), a1 = min(ey, 159);
        float g0r = grid[pb + a0 * 160], g1r = grid[pb + a1 * 160];
        g0 = (ey >= 1)   ? g0r : 1.0f;
        g1 = (ey <= 159) ? g1r : 1.0f;
        int b = (ex * C + ey) * C + ez;
        q0 = b - C * C - 1; q1 = b - 1; q2 = b; q3 = b - C * C;
    } else {
        int i2 = rem % 161; int r = rem / 161; int i1 = r % 160; int i0 = r / 160;
        int ex = i0 + 1, ey = i1 + 1, ez = i2;          // ez in [0,160]
        int pb = ((ex - 1) * 160 + i1) * 160;
        int a0 = max(ez - 1, 0), a1 = min(ez, 159);
        float g0r = grid[pb + a0], g1r = grid[pb + a1];
        g0 = (ez >= 1)   ? g0r : 1.0f;
        g1 = (ez <= 159) ? g1r : 1.0f;
        int b = (ex * C + ey) * C + ez;
        q0 = b - C * C - C; q1 = b - C; q2 = b; q3 = b - C * C;
    }
    f32x4 w;
    bool m = (g0 < 0.f) != (g1 < 0.f);
    if (!m) {
        w.x = w.y = w.z = w.w = -1.0f;
    } else {
        int a0, a1, a2, a3;
        if (g0 < 0.f) { a0 = q0; a1 = q1; a2 = q2; a3 = q3; }
        else          { a0 = q3; a1 = q2; a2 = q1; a3 = q0; }
        w.x = bf16r((float)a0);
        w.y = bf16r((float)a1);
        w.z = bf16r((float)a2);
        w.w = bf16r((float)a3);
    }
    return w;
}

// Quads body: direct misaligned dwordx4 store, NON-TEMPORAL (nt): output is
// write-once -- don't let 198 MB of stores evict the L2-resident grid.
__device__ __forceinline__ void quads_body(int qb, int t,
                                           const float* __restrict__ grid,
                                           float* __restrict__ out) {
    int a = qb / QBPA;
    int lb = qb - a * QBPA;
    int rem = lb * 256 + t;
    f32x4 w = quad_vals(grid, a, rem);
    int q = a * APQ + rem;
    float* gp = out + NVERT_ELEMS + ((size_t)q << 2);
    asm volatile("global_store_dwordx4 %0, %1, off nt"
                 :: "v"(gp), "v"(w) : "memory");
}

// Concatenated fusion: blocks [0,NVB) run verts, [NVB,NTOT) run quads.
__global__ __launch_bounds__(256) void dmc_fused(const float* __restrict__ grid,
                                                 const float* __restrict__ deform,
                                                 float* __restrict__ out) {
    __shared__ __align__(16) float sv[768];
    int b = blockIdx.x, t = threadIdx.x;
    if (b < NVB) {
        verts_body(b, t, grid, deform, out, sv);
    } else {
        quads_body(b - NVB, t, grid, out);
    }
}

extern "C" void kernel_launch(void* const* d_in, const int* in_sizes, int n_in,
                              void* d_out, int out_size, void* d_ws, size_t ws_size,
                              hipStream_t stream) {
    const float* grid   = (const float*)d_in[0];
    const float* deform = (const float*)d_in[1];
    float* out = (float*)d_out;

    hipLaunchKernelGGL(dmc_fused, dim3(NTOT), dim3(256), 0, stream, grid, deform, out);
}